// Round 8
// baseline (397.552 us; speedup 1.0000x reference)
//
#include <hip/hip_runtime.h>
#include <hip/hip_bf16.h>

// ---------------- problem constants ----------------
#define D_DIM 2048
#define HE_DIM 1024
#define E_NUM 8
#define T_NUM 4096
#define TK_NUM 8192           // T * K (top-2)
#define RTILE 64              // row (M) tile
#define NTILE 128             // col (N) tile
#define BK 64                 // K tile (proven conflict-free swizzle, 128B rows)
#define MAXROWS 8704          // TK + E*RTILE padding
#define MAXMT 136             // max m-tiles: 128 + 8
#define GATE_BLOCKS 256       // gate region of the merged gate+cvtWup kernel
#define CVTUP_BLOCKS 2048     // Wup-converter region (exactly 8 iters/thread)
#define CVT_Y 32              // Wdown-converter rows prepended to k_up's grid
#define W_N4 (E_NUM * HE_DIM * D_DIM / 4)   // 4194304 float4 per weight tensor

// meta (int) layout in workspace — counters padded to 128 B (32 ints).
#define M_CNT(e)  ((e) * 32)          // [0,256)   per-expert token count
#define M_FILL(e) (256 + (e) * 32)    // [256,512) atomic fill cursor
#define M_OFF  512                    // [8] padded row base per expert
#define M_NMT  520                    // [1] number of m-tiles
#define M_TE   528                    // [136] m-tile -> expert
#define M_TB   664                    // [136] m-tile -> global row base
#define M_TICKET 800                  // [1] gate last-block ticket
#define M_INTS 1024

typedef unsigned short u16;
typedef __attribute__((ext_vector_type(8))) short bf16x8;  // 8 bf16 in 4 VGPRs
typedef __attribute__((ext_vector_type(4))) float f32x4;

// workspace offsets (bytes)
// xb [0,16M) and wupb are dead after k_up; slot [T][2][D] bf16 (33.5M)
// overlaps them (k_down/k_combine run strictly after k_up on the stream).
#define OFF_XB   ((size_t)0)                                     // [T][D] bf16  16 MB
#define OFF_WUPB (OFF_XB + (size_t)T_NUM * D_DIM * 2)            // [E][HE][D] bf16 33.5 MB
#define OFF_SLOT ((size_t)0)                                     // [T][2][D] bf16 33.5 MB (overlap)
#define OFF_WDNB (OFF_WUPB + (size_t)E_NUM * HE_DIM * D_DIM * 2) // [E][D][HE] bf16 33.5 MB
#define OFF_H    (OFF_WDNB + (size_t)E_NUM * D_DIM * HE_DIM * 2) // [MAXROWS][HE] bf16 17.8 MB
#define OFF_SCR  (OFF_H + (size_t)MAXROWS * HE_DIM * 2)          // [TK] f32 slot score
#define OFF_EIDX (OFF_SCR + (size_t)TK_NUM * 4)                  // [TK] int slot expert
#define OFF_RT   (OFF_EIDX + (size_t)TK_NUM * 4)                 // [MAXROWS] int row->slot id
#define OFF_RS   (OFF_RT + (size_t)MAXROWS * 4)                  // [MAXROWS] f32 row score
#define OFF_META (OFF_RS + (size_t)MAXROWS * 4)                  // ints

__device__ __forceinline__ u16 f2bf(float f) {
  unsigned u = __float_as_uint(f);
  u += 0x7FFFu + ((u >> 16) & 1u);   // round-to-nearest-even
  return (u16)(u >> 16);
}
__device__ __forceinline__ float bf_lo(unsigned u) { return __uint_as_float(u << 16); }
__device__ __forceinline__ float bf_hi(unsigned u) { return __uint_as_float(u & 0xFFFF0000u); }

__device__ __forceinline__ void gload16(const void* g, void* l) {
  // async global->LDS, 16B per lane; LDS dest = wave-uniform base + lane*16
  __builtin_amdgcn_global_load_lds((const __attribute__((address_space(1))) void*)g,
                                   (__attribute__((address_space(3))) void*)l,
                                   16, 0, 0);
}

// ---------------- init: meta zero, rows poisoned to "padding" ----------------
__global__ void k_init(int* __restrict__ meta, int* __restrict__ rows_slot,
                       float* __restrict__ rowscore) {
  int i = blockIdx.x * blockDim.x + threadIdx.x;
  if (i < M_INTS) meta[i] = 0;
  if (i < MAXROWS) { rows_slot[i] = -1; rowscore[i] = 0.0f; }
}

// ---------------- gate (+ Wup f32->bf16 conversion in extra blocks) ----------------
// Blocks [0,256): gate. Blocks [256, 256+2048): stream-convert Wup. The gate is
// latency-bound (~8us) and uses ~0 HBM BW; the converter is pure BW — merged,
// the launch costs ~max(gate, cvt-BW) instead of the sum. Last GATE block
// (device ticket) computes the offsets + tile map.
__global__ __launch_bounds__(256) void k_gate(
    const float4* __restrict__ x4, const float4* __restrict__ Wg1_4,
    const float* __restrict__ Wg2, ushort4* __restrict__ xb4,
    int* __restrict__ eidx, float* __restrict__ scr, int* __restrict__ meta,
    const float4* __restrict__ Wup4, ushort4* __restrict__ wupb4) {
  const int tid = threadIdx.x;

  if (blockIdx.x >= GATE_BLOCKS) {
    // ---- Wup converter region: 2048 blocks x 256 thr -> exactly 8 iters ----
    int i = (blockIdx.x - GATE_BLOCKS) * 256 + tid;
    const int st = CVTUP_BLOCKS * 256;          // 524288; W_N4 / st == 8 exact
#pragma unroll 4
    for (; i < W_N4; i += st) {
      float4 v = Wup4[i];
      ushort4 o;
      o.x = f2bf(v.x); o.y = f2bf(v.y); o.z = f2bf(v.z); o.w = f2bf(v.w);
      wupb4[i] = o;
    }
    return;
  }

  __shared__ float4 wg1s[E_NUM * (D_DIM / 4)];   // 8*512*16B = 64 KB
  __shared__ int cnt_s[E_NUM];
  __shared__ int lastf;
  if (tid < E_NUM) cnt_s[tid] = 0;
#pragma unroll
  for (int i = 0; i < 16; ++i) wg1s[tid + i * 256] = Wg1_4[tid + i * 256];
  __syncthreads();

  const int w = tid >> 6;
  const int lane = tid & 63;
  for (int j = 0; j < 4; ++j) {
    const int t = blockIdx.x * 16 + w * 4 + j;
    float acc[E_NUM];
#pragma unroll
    for (int e = 0; e < E_NUM; ++e) acc[e] = 0.f;
#pragma unroll
    for (int i = 0; i < 8; ++i) {
      const int c = lane + i * 64;                 // float4 index within row (0..511)
      float4 xv = x4[(size_t)t * 512 + c];
      ushort4 o;
      o.x = f2bf(xv.x); o.y = f2bf(xv.y); o.z = f2bf(xv.z); o.w = f2bf(xv.w);
      xb4[(size_t)t * 512 + c] = o;
#pragma unroll
      for (int e = 0; e < E_NUM; ++e) {
        float4 wv = wg1s[e * 512 + c];
        acc[e] += xv.x * wv.x + xv.y * wv.y + xv.z * wv.z + xv.w * wv.w;
      }
    }
#pragma unroll
    for (int e = 0; e < E_NUM; ++e) {
      float v = acc[e];
#pragma unroll
      for (int off = 32; off; off >>= 1) v += __shfl_xor(v, off, 64);
      acc[e] = v;
    }
    if (lane == 0) {
      float l1[E_NUM], lg[E_NUM];
#pragma unroll
      for (int e = 0; e < E_NUM; ++e) l1[e] = tanhf(acc[e]);
#pragma unroll
      for (int i = 0; i < E_NUM; ++i) {
        float s = 0.f;
#pragma unroll
        for (int e = 0; e < E_NUM; ++e) s += l1[e] * Wg2[i * E_NUM + e];
        lg[i] = s;
      }
      // stable top-2 (lowest index wins ties, like jax.lax.top_k)
      int i0 = 0; float v0 = lg[0];
#pragma unroll
      for (int i = 1; i < E_NUM; ++i) if (lg[i] > v0) { v0 = lg[i]; i0 = i; }
      int i1 = -1; float v1 = -3.4e38f;
#pragma unroll
      for (int i = 0; i < E_NUM; ++i) if (i != i0 && lg[i] > v1) { v1 = lg[i]; i1 = i; }
      float e1 = __expf(v1 - v0);
      float s0 = 1.f / (1.f + e1);
      float s1 = e1 * s0;
      eidx[t * 2] = i0; eidx[t * 2 + 1] = i1;
      scr[t * 2] = s0;  scr[t * 2 + 1] = s1;
      atomicAdd(&cnt_s[i0], 1);      // LDS atomic — block-local, cheap
      atomicAdd(&cnt_s[i1], 1);
    }
  }
  __syncthreads();
  if (tid < E_NUM) atomicAdd(&meta[M_CNT(tid)], cnt_s[tid]);  // 8/block, padded lines

  // ---- last GATE block: compute offsets + tile map ----
  if (tid == 0) {
    __threadfence();
    lastf = (atomicAdd(&meta[M_TICKET], 1) == GATE_BLOCKS - 1);
  }
  __syncthreads();
  if (lastf && tid < 64) {
    const int l2 = tid;
    int cnt = (l2 < E_NUM) ? atomicAdd(&meta[M_CNT(l2)], 0) : 0;
    int tiles = (cnt + RTILE - 1) / RTILE;
    int pre = tiles;
#pragma unroll
    for (int off = 1; off < E_NUM; off <<= 1) {
      int v = __shfl_up(pre, off, 64);
      if (l2 >= off && l2 < E_NUM) pre += v;
    }
    int tb_excl = pre - tiles;               // exclusive prefix (valid lanes 0..7)
    if (l2 < E_NUM) meta[M_OFF + l2] = tb_excl * RTILE;
    const int nmt = __shfl(pre, E_NUM - 1, 64);
    if (l2 == 0) meta[M_NMT] = nmt;
    int tb[E_NUM];
#pragma unroll
    for (int k = 0; k < E_NUM; ++k) tb[k] = __shfl(tb_excl, k, 64);
    for (int mt = l2; mt < nmt; mt += 64) {
      int e = 0;
#pragma unroll
      for (int k = 1; k < E_NUM; ++k) if (mt >= tb[k]) e = k;
      meta[M_TE + mt] = e;
      meta[M_TB + mt] = mt * RTILE;          // tile bases are contiguous multiples of RTILE
    }
  }
}

// ---------------- compaction: wave-aggregated fetch-add ----------------
__global__ void k_assign(const int* __restrict__ eidx, const float* __restrict__ scr,
                         int* __restrict__ meta, int* __restrict__ rows_slot,
                         float* __restrict__ rowscore) {
  int i = blockIdx.x * blockDim.x + threadIdx.x;
  const int lane = threadIdx.x & 63;
  int e = eidx[i];
  int pos = 0;
#pragma unroll
  for (int ex = 0; ex < E_NUM; ++ex) {
    unsigned long long m = __ballot(e == ex);
    if (e == ex) {
      int leader = __ffsll((long long)m) - 1;
      int rank = __popcll(m & ((1ull << lane) - 1ull));
      int b = 0;
      if (lane == leader) b = atomicAdd(&meta[M_FILL(ex)], __popcll(m));
      b = __shfl(b, leader, 64);
      pos = b + rank;
    }
  }
  int r = meta[M_OFF + e] + pos;
  rows_slot[r] = i;            // slot id (token = i>>1)
  rowscore[r] = scr[i];
}

// ---------------- grouped up-GEMM (+ Wdown conversion in extra blocks) ----------------
// GEMM structure identical to r7's best (64x128 tile, 4 waves, 2 LDS bufs =
// 48 KB -> 3 blocks/CU, conflict-free XOR swizzle). Blocks with blockIdx.y <
// CVT_Y (dispatched FIRST) stream-convert Wdown f32->bf16: k_up runs at <30%
// of HBM BW, so the ~100 MB of converter traffic hides under the GEMM.
// k_down's dependency on wdnb is satisfied by the kernel boundary.
__global__ __launch_bounds__(256) void k_up(
    const u16* __restrict__ xb, const u16* __restrict__ wupb,
    const float* __restrict__ bup, const int* __restrict__ meta,
    const int* __restrict__ rows_slot, u16* __restrict__ hbuf,
    const float4* __restrict__ Wdn4, ushort4* __restrict__ wdnb4) {
  const int tid = threadIdx.x;

  if (blockIdx.y < CVT_Y) {
    // ---- Wdown converter: 32x8 = 256 blocks; 16 iters x 4 float4 exact ----
    const int idx = (blockIdx.y * 8 + (int)blockIdx.x) * 256 + tid;  // [0, 65536)
    const int st4 = CVT_Y * 8 * 256 * 4;        // 262144 f4/iter; W_N4/st4 == 16
#pragma unroll 2
    for (int base = idx * 4; base < W_N4; base += st4) {
      float4 v0 = Wdn4[base], v1 = Wdn4[base + 1], v2 = Wdn4[base + 2], v3 = Wdn4[base + 3];
      ushort4 o0, o1, o2, o3;
      o0.x = f2bf(v0.x); o0.y = f2bf(v0.y); o0.z = f2bf(v0.z); o0.w = f2bf(v0.w);
      o1.x = f2bf(v1.x); o1.y = f2bf(v1.y); o1.z = f2bf(v1.z); o1.w = f2bf(v1.w);
      o2.x = f2bf(v2.x); o2.y = f2bf(v2.y); o2.z = f2bf(v2.z); o2.w = f2bf(v2.w);
      o3.x = f2bf(v3.x); o3.y = f2bf(v3.y); o3.z = f2bf(v3.z); o3.w = f2bf(v3.w);
      wdnb4[base] = o0; wdnb4[base + 1] = o1; wdnb4[base + 2] = o2; wdnb4[base + 3] = o3;
    }
    return;
  }

  const int mt = blockIdx.y - CVT_Y;
  if (mt >= meta[M_NMT]) return;
  const int e = meta[M_TE + mt];
  const int mbase = meta[M_TB + mt];
  const int nt = blockIdx.x;

  __shared__ u16 As[2][RTILE * BK];   // 2 x 8 KB
  __shared__ u16 Bs[2][NTILE * BK];   // 2 x 16 KB

  const int lane = tid & 63;
  const int w = tid >> 6;                                // 0..3
  const int r0 = tid >> 3;                               // staged row 0..31
  const int cb = (((tid & 7) ^ (r0 & 7)) * 8);           // swizzled k-chunk (elements)

  const u16* gA[2];
  const u16* gB[4];
#pragma unroll
  for (int j = 0; j < 2; ++j) {
    int s = rows_slot[mbase + r0 + 32 * j]; if (s < 0) s = 0;
    gA[j] = xb + (size_t)(s >> 1) * D_DIM + cb;
  }
#pragma unroll
  for (int j = 0; j < 4; ++j)
    gB[j] = wupb + ((size_t)e * HE_DIM + nt * NTILE + r0 + 32 * j) * D_DIM + cb;

  const int wm = (w & 1) * 32;
  const int wn = (w >> 1) * 64;
  const int quad = lane >> 4;
  const int l16 = lane & 15;
  const int sw = l16 & 7;

  f32x4 acc[2][4] = {};

#define STAGE_UP(buf, k0) \
  { gload16(gA[0] + (k0), &As[buf][tid * 8]);        \
    gload16(gA[1] + (k0), &As[buf][tid * 8 + 2048]); \
    gload16(gB[0] + (k0), &Bs[buf][tid * 8]);        \
    gload16(gB[1] + (k0), &Bs[buf][tid * 8 + 2048]); \
    gload16(gB[2] + (k0), &Bs[buf][tid * 8 + 4096]); \
    gload16(gB[3] + (k0), &Bs[buf][tid * 8 + 6144]); }

  STAGE_UP(0, 0);
  __syncthreads();                      // tile 0 resident
  int cur = 0;
  for (int k0 = 0; k0 < D_DIM; k0 += BK) {
    if (k0 + BK < D_DIM) STAGE_UP(cur ^ 1, k0 + BK);   // prefetch next tile
    const u16* pa0 = &As[cur][(wm + l16) * BK];
    const u16* pb0 = &Bs[cur][(wn + l16) * BK];
#pragma unroll
    for (int h = 0; h < 2; ++h) {
      const int off = ((h * 4 + quad) ^ sw) * 8;
      bf16x8 af[2], bfr[4];
#pragma unroll
      for (int i = 0; i < 2; ++i) af[i] = *(const bf16x8*)(pa0 + i * 16 * BK + off);
#pragma unroll
      for (int i = 0; i < 4; ++i) bfr[i] = *(const bf16x8*)(pb0 + i * 16 * BK + off);
#pragma unroll
      for (int mi = 0; mi < 2; ++mi)
#pragma unroll
        for (int ni = 0; ni < 4; ++ni)
          acc[mi][ni] = __builtin_amdgcn_mfma_f32_16x16x32_bf16(af[mi], bfr[ni], acc[mi][ni], 0, 0, 0);
    }
    __syncthreads();                    // drains prefetch + LDS read completion
    cur ^= 1;
  }

#pragma unroll
  for (int mi = 0; mi < 2; ++mi) {
    const int m = wm + mi * 16 + quad * 4;
#pragma unroll
    for (int ni = 0; ni < 4; ++ni) {
      const int ng = nt * NTILE + wn + ni * 16 + l16;
      const float bias = bup[e * HE_DIM + ng];
#pragma unroll
      for (int r = 0; r < 4; ++r) {
        float v = acc[mi][ni][r] + bias;
        v = v / (1.0f + __expf(-v));     // silu
        hbuf[(size_t)(mbase + m + r) * HE_DIM + ng] = f2bf(v);
      }
    }
  }
}

// ---------------- grouped down-GEMM: slot[s] = score * (h @ Wdown[e]^T + bdown[e]) ----------------
__global__ __launch_bounds__(256) void k_down(
    const u16* __restrict__ hbuf, const u16* __restrict__ wdnb,
    const float* __restrict__ bdown, const int* __restrict__ meta,
    const int* __restrict__ rows_slot, const float* __restrict__ rowscore,
    u16* __restrict__ slot) {
  const int mt = blockIdx.y;
  if (mt >= meta[M_NMT]) return;
  const int e = meta[M_TE + mt];
  const int mbase = meta[M_TB + mt];
  const int nt = blockIdx.x;

  __shared__ u16 As[2][RTILE * BK];
  __shared__ u16 Bs[2][NTILE * BK];

  const int tid = threadIdx.x;
  const int lane = tid & 63;
  const int w = tid >> 6;
  const int r0 = tid >> 3;
  const int cb = (((tid & 7) ^ (r0 & 7)) * 8);

  const u16* gA[2];
  const u16* gB[4];
#pragma unroll
  for (int j = 0; j < 2; ++j)
    gA[j] = hbuf + (size_t)(mbase + r0 + 32 * j) * HE_DIM + cb;
#pragma unroll
  for (int j = 0; j < 4; ++j)
    gB[j] = wdnb + ((size_t)e * D_DIM + nt * NTILE + r0 + 32 * j) * HE_DIM + cb;

  const int wm = (w & 1) * 32;
  const int wn = (w >> 1) * 64;
  const int quad = lane >> 4;
  const int l16 = lane & 15;
  const int sw = l16 & 7;

  f32x4 acc[2][4] = {};

#define STAGE_DN(buf, k0) \
  { gload16(gA[0] + (k0), &As[buf][tid * 8]);        \
    gload16(gA[1] + (k0), &As[buf][tid * 8 + 2048]); \
    gload16(gB[0] + (k0), &Bs[buf][tid * 8]);        \
    gload16(gB[1] + (k0), &Bs[buf][tid * 8 + 2048]); \
    gload16(gB[2] + (k0), &Bs[buf][tid * 8 + 4096]); \
    gload16(gB[3] + (k0), &Bs[buf][tid * 8 + 6144]); }

  STAGE_DN(0, 0);
  __syncthreads();
  int cur = 0;
  for (int k0 = 0; k0 < HE_DIM; k0 += BK) {
    if (k0 + BK < HE_DIM) STAGE_DN(cur ^ 1, k0 + BK);
    const u16* pa0 = &As[cur][(wm + l16) * BK];
    const u16* pb0 = &Bs[cur][(wn + l16) * BK];
#pragma unroll
    for (int h = 0; h < 2; ++h) {
      const int off = ((h * 4 + quad) ^ sw) * 8;
      bf16x8 af[2], bfr[4];
#pragma unroll
      for (int i = 0; i < 2; ++i) af[i] = *(const bf16x8*)(pa0 + i * 16 * BK + off);
#pragma unroll
      for (int i = 0; i < 4; ++i) bfr[i] = *(const bf16x8*)(pb0 + i * 16 * BK + off);
#pragma unroll
      for (int mi = 0; mi < 2; ++mi)
#pragma unroll
        for (int ni = 0; ni < 4; ++ni)
          acc[mi][ni] = __builtin_amdgcn_mfma_f32_16x16x32_bf16(af[mi], bfr[ni], acc[mi][ni], 0, 0, 0);
    }
    __syncthreads();
    cur ^= 1;
  }

#pragma unroll
  for (int mi = 0; mi < 2; ++mi) {
    const int m = wm + mi * 16 + quad * 4;
#pragma unroll
    for (int r = 0; r < 4; ++r) {
      const int rg = mbase + m + r;
      const int s = rows_slot[rg];
      const float sc = rowscore[rg];
      if (s < 0) continue;               // padding row
      u16* dst = slot + (size_t)s * D_DIM;
#pragma unroll
      for (int ni = 0; ni < 4; ++ni) {
        const int ng = nt * NTILE + wn + ni * 16 + l16;
        float v = (acc[mi][ni][r] + bdown[e * D_DIM + ng]) * sc;
        dst[ng] = f2bf(v);
      }
    }
  }
}

// ---------------- combine: out[t] = slot[t][0] + slot[t][1] (fully coalesced) ----------------
__global__ __launch_bounds__(256) void k_combine(const u16* __restrict__ slot,
                                                 float* __restrict__ out) {
  int i = blockIdx.x * blockDim.x + threadIdx.x;   // one 16B chunk (8 bf16) per thread
  int t = i >> 8;                                  // D/8 = 256 chunks per token
  int c = i & 255;
  const uint4* p0 = (const uint4*)(slot + (size_t)(t * 2) * D_DIM) + c;
  const uint4* p1 = (const uint4*)(slot + (size_t)(t * 2 + 1) * D_DIM) + c;
  uint4 a = *p0, b = *p1;
  float4 o0, o1;
  o0.x = bf_lo(a.x) + bf_lo(b.x);  o0.y = bf_hi(a.x) + bf_hi(b.x);
  o0.z = bf_lo(a.y) + bf_lo(b.y);  o0.w = bf_hi(a.y) + bf_hi(b.y);
  o1.x = bf_lo(a.z) + bf_lo(b.z);  o1.y = bf_hi(a.z) + bf_hi(b.z);
  o1.z = bf_lo(a.w) + bf_lo(b.w);  o1.w = bf_hi(a.w) + bf_hi(b.w);
  float4* po = (float4*)(out + (size_t)t * D_DIM) + c * 2;
  po[0] = o0;
  po[1] = o1;
}

// ---------------- launcher ----------------
extern "C" void kernel_launch(void* const* d_in, const int* in_sizes, int n_in,
                              void* d_out, int out_size, void* d_ws, size_t ws_size,
                              hipStream_t stream) {
  const float* x     = (const float*)d_in[0];
  const float* Wg1   = (const float*)d_in[1];
  const float* Wg2   = (const float*)d_in[2];
  const float* Wup   = (const float*)d_in[3];
  const float* bup   = (const float*)d_in[4];
  const float* Wdown = (const float*)d_in[5];
  const float* bdown = (const float*)d_in[6];
  float* out = (float*)d_out;

  char* ws = (char*)d_ws;
  u16*   xb         = (u16*)(ws + OFF_XB);
  u16*   wupb       = (u16*)(ws + OFF_WUPB);
  u16*   wdnb       = (u16*)(ws + OFF_WDNB);
  u16*   hbuf       = (u16*)(ws + OFF_H);
  u16*   slotbuf    = (u16*)(ws + OFF_SLOT);
  float* scr        = (float*)(ws + OFF_SCR);
  int*   eidx       = (int*)(ws + OFF_EIDX);
  int*   rows_slot  = (int*)(ws + OFF_RT);
  float* rowscore   = (float*)(ws + OFF_RS);
  int*   meta       = (int*)(ws + OFF_META);

  k_init<<<(MAXROWS + 255) / 256, 256, 0, stream>>>(meta, rows_slot, rowscore);
  k_gate<<<GATE_BLOCKS + CVTUP_BLOCKS, 256, 0, stream>>>(
      (const float4*)x, (const float4*)Wg1, Wg2, (ushort4*)xb, eidx, scr, meta,
      (const float4*)Wup, (ushort4*)wupb);
  k_assign<<<TK_NUM / 256, 256, 0, stream>>>(eidx, scr, meta, rows_slot, rowscore);
  k_up<<<dim3(HE_DIM / NTILE, CVT_Y + MAXMT), 256, 0, stream>>>(
      xb, wupb, bup, meta, rows_slot, hbuf, (const float4*)Wdown, (ushort4*)wdnb);
  k_down<<<dim3(D_DIM / NTILE, MAXMT), 256, 0, stream>>>(hbuf, wdnb, bdown, meta,
                                                         rows_slot, rowscore, slotbuf);
  k_combine<<<T_NUM * D_DIM / 8 / 256, 256, 0, stream>>>(slotbuf, out);
}